// Round 1
// baseline (691.957 us; speedup 1.0000x reference)
//
#include <hip/hip_runtime.h>
#include <cfloat>
#include <cmath>

// Problem constants
constexpr int Bn  = 4096;   // batch
constexpr int Rn  = 1000;   // rels
constexpr int Vn  = 2000;   // vocab
constexpr int Dn  = 300;    // emb dim
constexpr int FIN = 600;    // 2*Dn
constexpr int LAT = 512;
constexpr int ZD  = 512;
constexpr int TOPK_N = 2;
constexpr int DISK_N = 20;
constexpr float TEMP_INV = 1.0f / 0.07f;

// ---------------------------------------------------------------------------
// Top-k: one wave (64 threads) per row. Finds top-2 (desc) and bottom-20
// (asc), JAX-stable tie-break (lower index wins). Stores rel_key = rels[:,1]
// values directly.
// ---------------------------------------------------------------------------
__global__ __launch_bounds__(64) void topk_kernel(
    const float* __restrict__ logits, const int* __restrict__ rels,
    int* __restrict__ pos_keys, int* __restrict__ neg_keys) {
  const int b = blockIdx.x;
  const int lane = threadIdx.x;
  const float* row = logits + (size_t)b * Rn;

  float w[16];
#pragma unroll
  for (int i = 0; i < 16; ++i) {
    int idx = i * 64 + lane;
    w[i] = (idx < Rn) ? row[idx] : 0.0f;
  }

  float v[16];
  // ---- bottom-20 (== top_k(-logits, 20)) ----
#pragma unroll
  for (int i = 0; i < 16; ++i) {
    int idx = i * 64 + lane;
    v[i] = (idx < Rn) ? w[i] : FLT_MAX;
  }
  for (int t = 0; t < DISK_N; ++t) {
    float bv = FLT_MAX;
    int bi = 0x7fffffff;
#pragma unroll
    for (int i = 0; i < 16; ++i) {
      int idx = i * 64 + lane;
      if (v[i] < bv || (v[i] == bv && idx < bi)) { bv = v[i]; bi = idx; }
    }
    for (int off = 32; off >= 1; off >>= 1) {
      float ov = __shfl_xor(bv, off);
      int oi = __shfl_xor(bi, off);
      if (ov < bv || (ov == bv && oi < bi)) { bv = ov; bi = oi; }
    }
    if ((bi & 63) == lane) v[bi >> 6] = FLT_MAX;
    if (lane == 0) neg_keys[b * DISK_N + t] = rels[bi * 2 + 1];
  }
  // ---- top-2 ----
#pragma unroll
  for (int i = 0; i < 16; ++i) {
    int idx = i * 64 + lane;
    v[i] = (idx < Rn) ? w[i] : -FLT_MAX;
  }
  for (int t = 0; t < TOPK_N; ++t) {
    float bv = -FLT_MAX;
    int bi = 0x7fffffff;
#pragma unroll
    for (int i = 0; i < 16; ++i) {
      int idx = i * 64 + lane;
      if (v[i] > bv || (v[i] == bv && idx < bi)) { bv = v[i]; bi = idx; }
    }
    for (int off = 32; off >= 1; off >>= 1) {
      float ov = __shfl_xor(bv, off);
      int oi = __shfl_xor(bi, off);
      if (ov > bv || (ov == bv && oi < bi)) { bv = ov; bi = oi; }
    }
    if ((bi & 63) == lane) v[bi >> 6] = -FLT_MAX;
    if (lane == 0) pos_keys[b * TOPK_N + t] = rels[bi * 2 + 1];
  }
}

// ---------------------------------------------------------------------------
// Gather x[b] = concat(rel_emb[key0], rel_emb[key1])  (B x 600)
// ---------------------------------------------------------------------------
__global__ __launch_bounds__(128) void gather_x_kernel(
    const int* __restrict__ pos_keys, const float* __restrict__ rel_emb,
    float* __restrict__ x) {
  const int b = blockIdx.x;
  const int k0 = pos_keys[b * 2 + 0];
  const int k1 = pos_keys[b * 2 + 1];
  const float* e0 = rel_emb + (size_t)k0 * Dn;
  const float* e1 = rel_emb + (size_t)k1 * Dn;
  float* xb = x + (size_t)b * FIN;
  for (int d = threadIdx.x; d < Dn; d += blockDim.x) {
    xb[d] = e0[d];
    xb[Dn + d] = e1[d];
  }
}

// ---------------------------------------------------------------------------
// Generic fp32 tiled GEMM: C = act(A @ W + bias)
// A: MxK row-major, W: KxN row-major, C: MxN row-major.
// 64x64 tile, 256 threads, 4x4 per thread, K-step 16. Fully guarded.
// ACT: 0=none, 1=tanh, 2=sigmoid, 3=relu
// ---------------------------------------------------------------------------
template <int ACT>
__global__ __launch_bounds__(256) void gemm_bias_act(
    const float* __restrict__ A, const float* __restrict__ W,
    const float* __restrict__ bias, float* __restrict__ C,
    int M, int N, int K) {
  __shared__ float As[16][64 + 4];  // [k][m], padded (2-way max on r/w)
  __shared__ float Bs[16][64];      // [k][n]

  const int tid = threadIdx.x;
  const int tx = tid & 15;   // n-group
  const int ty = tid >> 4;   // m-group
  const int m0 = blockIdx.x * 64;
  const int n0 = blockIdx.y * 64;

  float acc[4][4] = {};

  for (int k0 = 0; k0 < K; k0 += 16) {
    // A tile 64x16 -> As[k][m]
#pragma unroll
    for (int i = 0; i < 4; ++i) {
      int idx = tid + i * 256;
      int m = idx >> 4;
      int k = idx & 15;
      int gm = m0 + m, gk = k0 + k;
      float val = 0.0f;
      if (gm < M && gk < K) val = A[(size_t)gm * K + gk];
      As[k][m] = val;
    }
    // B tile 16x64 -> Bs[k][n]
#pragma unroll
    for (int i = 0; i < 4; ++i) {
      int idx = tid + i * 256;
      int k = idx >> 6;
      int n = idx & 63;
      int gk = k0 + k, gn = n0 + n;
      float val = 0.0f;
      if (gk < K && gn < N) val = W[(size_t)gk * N + gn];
      Bs[k][n] = val;
    }
    __syncthreads();

#pragma unroll
    for (int kk = 0; kk < 16; ++kk) {
      float4 a4 = *reinterpret_cast<const float4*>(&As[kk][ty * 4]);
      float4 b4 = *reinterpret_cast<const float4*>(&Bs[kk][tx * 4]);
      float a[4] = {a4.x, a4.y, a4.z, a4.w};
      float bb[4] = {b4.x, b4.y, b4.z, b4.w};
#pragma unroll
      for (int i = 0; i < 4; ++i)
#pragma unroll
        for (int j = 0; j < 4; ++j)
          acc[i][j] = fmaf(a[i], bb[j], acc[i][j]);
    }
    __syncthreads();
  }

#pragma unroll
  for (int i = 0; i < 4; ++i) {
    int gm = m0 + ty * 4 + i;
    if (gm >= M) continue;
#pragma unroll
    for (int j = 0; j < 4; ++j) {
      int gn = n0 + tx * 4 + j;
      if (gn >= N) continue;
      float vv = acc[i][j] + bias[gn];
      if (ACT == 1) vv = tanhf(vv);
      else if (ACT == 2) vv = 1.0f / (1.0f + expf(-vv));
      else if (ACT == 3) vv = fmaxf(vv, 0.0f);
      C[(size_t)gm * N + gn] = vv;
    }
  }
}

// ---------------------------------------------------------------------------
// loss_vae partials: sum of (x - x_rec)^2, grid-stride; per-block partial.
// ---------------------------------------------------------------------------
__global__ __launch_bounds__(256) void vae_loss_partial(
    const float* __restrict__ x, const float* __restrict__ x_rec,
    float* __restrict__ partials) {
  const int n = Bn * FIN;
  float s = 0.0f;
  for (int i = blockIdx.x * blockDim.x + threadIdx.x; i < n;
       i += gridDim.x * blockDim.x) {
    float d = x[i] - x_rec[i];
    s = fmaf(d, d, s);
  }
  __shared__ float red[256];
  red[threadIdx.x] = s;
  __syncthreads();
  for (int off = 128; off >= 1; off >>= 1) {
    if (threadIdx.x < off) red[threadIdx.x] += red[threadIdx.x + off];
    __syncthreads();
  }
  if (threadIdx.x == 0) partials[blockIdx.x] = red[0];
}

// ---------------------------------------------------------------------------
// Contrastive loss: one wave per row. 21 dot products of 512 against the
// precomputed projection table, then log-softmax loss of class 0.
// ---------------------------------------------------------------------------
__global__ __launch_bounds__(64) void csl_kernel(
    const float* __restrict__ zp, const float* __restrict__ proj,
    const int* __restrict__ pos_keys, const int* __restrict__ neg_keys,
    float* __restrict__ row_loss) {
  const int b = blockIdx.x;
  const int lane = threadIdx.x;
  const float* z = zp + (size_t)b * ZD;
  float zr[8];
#pragma unroll
  for (int j = 0; j < 8; ++j) zr[j] = z[j * 64 + lane];

  float lg[21];
  for (int t = 0; t < 21; ++t) {
    int key = (t == 0) ? pos_keys[b * 2] : neg_keys[b * DISK_N + (t - 1)];
    const float* p = proj + (size_t)key * ZD;
    float acc = 0.0f;
#pragma unroll
    for (int j = 0; j < 8; ++j) acc = fmaf(zr[j], p[j * 64 + lane], acc);
    for (int off = 32; off >= 1; off >>= 1) acc += __shfl_xor(acc, off);
    lg[t] = acc * TEMP_INV;
  }
  float m = lg[0];
#pragma unroll
  for (int t = 1; t < 21; ++t) m = fmaxf(m, lg[t]);
  float se = 0.0f;
#pragma unroll
  for (int t = 0; t < 21; ++t) se += expf(lg[t] - m);
  float loss = m + logf(se) - lg[0];
  if (lane == 0) row_loss[b] = loss;
}

// ---------------------------------------------------------------------------
// Finalize: deterministic reduce of partials -> d_out[0], d_out[1];
// zero z_rel row 0.
// ---------------------------------------------------------------------------
__global__ __launch_bounds__(256) void finalize_kernel(
    const float* __restrict__ vae_partials, int n_vae,
    const float* __restrict__ row_loss, int n_rows, float* __restrict__ out) {
  __shared__ float red[256];
  const int tid = threadIdx.x;

  float s = 0.0f;
  for (int i = tid; i < n_vae; i += 256) s += vae_partials[i];
  red[tid] = s;
  __syncthreads();
  for (int off = 128; off >= 1; off >>= 1) {
    if (tid < off) red[tid] += red[tid + off];
    __syncthreads();
  }
  float loss_vae = red[0] * (1.0f / (float)FIN);
  __syncthreads();

  float s2 = 0.0f;
  for (int i = tid; i < n_rows; i += 256) s2 += row_loss[i];
  red[tid] = s2;
  __syncthreads();
  for (int off = 128; off >= 1; off >>= 1) {
    if (tid < off) red[tid] += red[tid + off];
    __syncthreads();
  }
  if (tid == 0) {
    out[0] = loss_vae;
    out[1] = red[0];
  }
  // z_rel row 0 = zeros
  for (int i = tid; i < ZD; i += 256) out[2 + i] = 0.0f;
}

// ---------------------------------------------------------------------------
extern "C" void kernel_launch(void* const* d_in, const int* in_sizes, int n_in,
                              void* d_out, int out_size, void* d_ws,
                              size_t ws_size, hipStream_t stream) {
  const float* logits = (const float*)d_in[0];
  const int*   rels   = (const int*)d_in[1];
  const float* rel_emb= (const float*)d_in[2];
  const float* We1 = (const float*)d_in[3];  const float* be1 = (const float*)d_in[4];
  const float* We2 = (const float*)d_in[5];  const float* be2 = (const float*)d_in[6];
  const float* Wd1 = (const float*)d_in[7];  const float* bd1 = (const float*)d_in[8];
  const float* Wd2 = (const float*)d_in[9];  const float* bd2 = (const float*)d_in[10];
  const float* Wz1 = (const float*)d_in[11]; const float* bz1 = (const float*)d_in[12];
  const float* Wz2 = (const float*)d_in[13]; const float* bz2 = (const float*)d_in[14];
  // Wi* (15-18) are value-identical to Wk* (19-22); use Wk* (the neg branch's)
  const float* Wk1 = (const float*)d_in[19]; const float* bk1 = (const float*)d_in[20];
  const float* Wk2 = (const float*)d_in[21]; const float* bk2 = (const float*)d_in[22];

  float* out = (float*)d_out;

  char* ws = (char*)d_ws;
  size_t off = 0;
  auto walloc = [&](size_t bytes) -> void* {
    void* p = ws + off;
    off = (off + bytes + 255) & ~(size_t)255;
    return p;
  };
  int*   pos_keys = (int*)walloc((size_t)Bn * 2 * sizeof(int));
  int*   neg_keys = (int*)walloc((size_t)Bn * DISK_N * sizeof(int));
  float* x        = (float*)walloc((size_t)Bn * FIN * sizeof(float));
  float* tmpA     = (float*)walloc((size_t)Bn * LAT * sizeof(float));
  float* z        = (float*)walloc((size_t)Bn * LAT * sizeof(float));
  float* x_rec    = (float*)walloc((size_t)Bn * FIN * sizeof(float));
  float* th       = (float*)walloc((size_t)Vn * LAT * sizeof(float));
  float* proj     = (float*)walloc((size_t)Vn * ZD * sizeof(float));
  float* vae_part = (float*)walloc(1024 * sizeof(float));
  float* row_loss = (float*)walloc((size_t)Bn * sizeof(float));
  (void)ws_size; (void)in_sizes; (void)n_in; (void)out_size;

  float* zp_out = out + 2 + ZD;  // z_rel rows 1..B

  auto grid_of = [](int M, int N) { return dim3((M + 63) / 64, (N + 63) / 64); };
  const dim3 blk(256);

  // 1. top-k indices -> keys
  topk_kernel<<<Bn, 64, 0, stream>>>(logits, rels, pos_keys, neg_keys);
  // 2. gather x
  gather_x_kernel<<<Bn, 128, 0, stream>>>(pos_keys, rel_emb, x);
  // 3-4. projection table over full vocab (serves pos_vec AND all neg_p)
  gemm_bias_act<3><<<grid_of(Vn, LAT), blk, 0, stream>>>(rel_emb, Wk1, bk1, th, Vn, LAT, Dn);
  gemm_bias_act<0><<<grid_of(Vn, ZD),  blk, 0, stream>>>(th, Wk2, bk2, proj, Vn, ZD, LAT);
  // 5-6. encoder
  gemm_bias_act<1><<<grid_of(Bn, LAT), blk, 0, stream>>>(x, We1, be1, tmpA, Bn, LAT, FIN);
  gemm_bias_act<1><<<grid_of(Bn, ZD),  blk, 0, stream>>>(tmpA, We2, be2, z, Bn, ZD, LAT);
  // 7-8. decoder
  gemm_bias_act<1><<<grid_of(Bn, LAT), blk, 0, stream>>>(z, Wd1, bd1, tmpA, Bn, LAT, ZD);
  gemm_bias_act<2><<<grid_of(Bn, FIN), blk, 0, stream>>>(tmpA, Wd2, bd2, x_rec, Bn, FIN, LAT);
  // 9-10. z_p head (written directly into d_out's z_rel rows 1..B)
  gemm_bias_act<3><<<grid_of(Bn, LAT), blk, 0, stream>>>(z, Wz1, bz1, tmpA, Bn, LAT, ZD);
  gemm_bias_act<0><<<grid_of(Bn, ZD),  blk, 0, stream>>>(tmpA, Wz2, bz2, zp_out, Bn, ZD, LAT);
  // 11. VAE loss partials
  vae_loss_partial<<<1024, 256, 0, stream>>>(x, x_rec, vae_part);
  // 12. contrastive per-row loss
  csl_kernel<<<Bn, 64, 0, stream>>>(zp_out, proj, pos_keys, neg_keys, row_loss);
  // 13. finalize losses + zero row 0
  finalize_kernel<<<1, 256, 0, stream>>>(vae_part, 1024, row_loss, Bn, out);
}

// Round 2
// 219.765 us; speedup vs baseline: 3.1486x; 3.1486x over previous
//
#include <hip/hip_runtime.h>
#include <hip/hip_bf16.h>
#include <cfloat>
#include <cmath>

typedef unsigned short u16;
typedef __attribute__((ext_vector_type(8))) short bf16x8;
typedef __attribute__((ext_vector_type(4))) float f32x4;

// Problem constants
constexpr int Bn  = 4096;   // batch
constexpr int Rn  = 1000;   // rels
constexpr int Vn  = 2000;   // vocab
constexpr int Dn  = 300;    // emb dim
constexpr int FIN = 600;    // 2*Dn
constexpr int LAT = 512;
constexpr int ZD  = 512;
constexpr int TOPK_N = 2;
constexpr int DISK_N = 20;
constexpr float TEMP_INV = 1.0f / 0.07f;

constexpr int KP_X   = 640;  // FIN=600 padded to 64-mult
constexpr int KP_REL = 320;  // Dn=300 padded
constexpr int VP     = 2048; // Vn padded to 128-mult (M-tiles)

__device__ inline u16 f2b(float v) {
  __hip_bfloat16 h = __float2bfloat16(v);
  return *reinterpret_cast<u16*>(&h);
}

// ---------------------------------------------------------------------------
// Top-k: one wave per row; JAX-stable tie-break (lower index wins).
// ---------------------------------------------------------------------------
__global__ __launch_bounds__(64) void topk_kernel(
    const float* __restrict__ logits, const int* __restrict__ rels,
    int* __restrict__ pos_keys, int* __restrict__ neg_keys) {
  const int b = blockIdx.x;
  const int lane = threadIdx.x;
  const float* row = logits + (size_t)b * Rn;

  float w[16];
#pragma unroll
  for (int i = 0; i < 16; ++i) {
    int idx = i * 64 + lane;
    w[i] = (idx < Rn) ? row[idx] : 0.0f;
  }

  float v[16];
#pragma unroll
  for (int i = 0; i < 16; ++i) {
    int idx = i * 64 + lane;
    v[i] = (idx < Rn) ? w[i] : FLT_MAX;
  }
  for (int t = 0; t < DISK_N; ++t) {
    float bv = FLT_MAX;
    int bi = 0x7fffffff;
#pragma unroll
    for (int i = 0; i < 16; ++i) {
      int idx = i * 64 + lane;
      if (v[i] < bv || (v[i] == bv && idx < bi)) { bv = v[i]; bi = idx; }
    }
    for (int off = 32; off >= 1; off >>= 1) {
      float ov = __shfl_xor(bv, off);
      int oi = __shfl_xor(bi, off);
      if (ov < bv || (ov == bv && oi < bi)) { bv = ov; bi = oi; }
    }
    if ((bi & 63) == lane) v[bi >> 6] = FLT_MAX;
    if (lane == 0) neg_keys[b * DISK_N + t] = rels[bi * 2 + 1];
  }
#pragma unroll
  for (int i = 0; i < 16; ++i) {
    int idx = i * 64 + lane;
    v[i] = (idx < Rn) ? w[i] : -FLT_MAX;
  }
  for (int t = 0; t < TOPK_N; ++t) {
    float bv = -FLT_MAX;
    int bi = 0x7fffffff;
#pragma unroll
    for (int i = 0; i < 16; ++i) {
      int idx = i * 64 + lane;
      if (v[i] > bv || (v[i] == bv && idx < bi)) { bv = v[i]; bi = idx; }
    }
    for (int off = 32; off >= 1; off >>= 1) {
      float ov = __shfl_xor(bv, off);
      int oi = __shfl_xor(bi, off);
      if (ov > bv || (ov == bv && oi < bi)) { bv = ov; bi = oi; }
    }
    if ((bi & 63) == lane) v[bi >> 6] = -FLT_MAX;
    if (lane == 0) pos_keys[b * TOPK_N + t] = rels[bi * 2 + 1];
  }
}

// ---------------------------------------------------------------------------
// Gather x[b] = concat(rel_emb[key0], rel_emb[key1]); fp32 (for loss) and
// bf16 zero-padded to KP_X (for MFMA GEMM A operand).
// ---------------------------------------------------------------------------
__global__ __launch_bounds__(128) void gather_x_kernel(
    const int* __restrict__ pos_keys, const float* __restrict__ rel_emb,
    float* __restrict__ x, u16* __restrict__ x_bf) {
  const int b = blockIdx.x;
  const int k0 = pos_keys[b * 2 + 0];
  const int k1 = pos_keys[b * 2 + 1];
  const float* e0 = rel_emb + (size_t)k0 * Dn;
  const float* e1 = rel_emb + (size_t)k1 * Dn;
  float* xb = x + (size_t)b * FIN;
  u16* xbb = x_bf + (size_t)b * KP_X;
  for (int d = threadIdx.x; d < KP_X; d += blockDim.x) {
    float v = 0.0f;
    if (d < Dn) v = e0[d];
    else if (d < FIN) v = e1[d - Dn];
    if (d < FIN) xb[d] = v;
    xbb[d] = f2b(v);
  }
}

// ---------------------------------------------------------------------------
// Fused weight convert+transpose: src K x N fp32 row-major ->
// dst Np x Kp bf16 row-major (dst[n][k] = src[k][n], zero pad).
// One 64x64 dst tile per block; LDS-staged so both phases coalesce.
// ---------------------------------------------------------------------------
struct TSeg {
  const float* src;
  u16* dst;
  int K, N, Kp, Np;
  int tile_end;  // exclusive prefix sum of tiles
};
struct TSegs { TSeg s[8]; };

__global__ __launch_bounds__(256) void convert_transpose_kernel(TSegs segs) {
  __shared__ float tile[64][65];
  int bid = blockIdx.x;
  int si = 0;
  while (si < 7 && bid >= segs.s[si].tile_end) ++si;
  const TSeg sg = segs.s[si];
  int t0 = (si == 0) ? 0 : segs.s[si - 1].tile_end;
  int tIdx = bid - t0;
  int tiles_k = sg.Kp >> 6;
  int tn0 = (tIdx / tiles_k) << 6;
  int tk0 = (tIdx % tiles_k) << 6;

  const int tid = threadIdx.x;
#pragma unroll
  for (int i = 0; i < 16; ++i) {
    int idx = tid + i * 256;
    int ko = idx >> 6, no = idx & 63;
    int gk = tk0 + ko, gn = tn0 + no;
    float v = 0.0f;
    if (gk < sg.K && gn < sg.N) v = sg.src[(size_t)gk * sg.N + gn];
    tile[ko][no] = v;
  }
  __syncthreads();
#pragma unroll
  for (int i = 0; i < 16; ++i) {
    int idx = tid + i * 256;
    int ko = idx & 63, no = idx >> 6;
    sg.dst[(size_t)(tn0 + no) * sg.Kp + tk0 + ko] = f2b(tile[ko][no]);
  }
}

// rel_emb (Vn x Dn fp32) -> rel_bf (VP x KP_REL bf16, zero-padded)
__global__ __launch_bounds__(256) void convert_rel_kernel(
    const float* __restrict__ rel_emb, u16* __restrict__ rel_bf) {
  const int total = VP * KP_REL;
  for (int i = blockIdx.x * 256 + threadIdx.x; i < total; i += gridDim.x * 256) {
    int m = i / KP_REL, k = i - m * KP_REL;
    float v = (m < Vn && k < Dn) ? rel_emb[(size_t)m * Dn + k] : 0.0f;
    rel_bf[i] = f2b(v);
  }
}

// ---------------------------------------------------------------------------
// bf16 MFMA GEMM: C = act(A @ W + bias)
// A: M x Kp bf16 row-major (rows padded to 128-mult, zero/garbage-safe)
// Bt: Np x Kp bf16 row-major  (= W^T, zero-padded)
// Tile 128x64, 4 waves (2x2), BK=64, mfma_f32_16x16x32_bf16.
// XOR swizzle elem ^= ((row&7)<<3) kills the stride-128B bank conflict.
// ACT: 0=none 1=tanh 2=sigmoid 3=relu
// ---------------------------------------------------------------------------
template <int ACT, bool OUT_BF16>
__global__ __launch_bounds__(256) void gemm_mfma(
    const u16* __restrict__ A, const u16* __restrict__ Bt,
    const float* __restrict__ bias, float* __restrict__ Cf,
    u16* __restrict__ Cb, int M, int N, int Kp, int ldc) {
  __shared__ u16 As[128 * 64];
  __shared__ u16 Bs[64 * 64];

  const int tid = threadIdx.x;
  const int lane = tid & 63;
  const int w = tid >> 6;
  const int wm = (w >> 1) * 64;
  const int wn = (w & 1) * 32;
  const int m0 = blockIdx.x * 128;
  const int n0 = blockIdx.y * 64;

  f32x4 acc[4][2];
#pragma unroll
  for (int i = 0; i < 4; ++i)
#pragma unroll
    for (int j = 0; j < 2; ++j) acc[i][j] = (f32x4)(0.0f);

  const int r = lane & 15;
  const int kq = lane >> 4;  // 0..3

  for (int k0 = 0; k0 < Kp; k0 += 64) {
    // stage A tile 128x64 (1024 16B-chunks)
#pragma unroll
    for (int i = 0; i < 4; ++i) {
      int c = tid + i * 256;
      int row = c >> 3, kc = (c & 7) * 8;
      bf16x8 v = *(const bf16x8*)(A + (size_t)(m0 + row) * Kp + k0 + kc);
      *(bf16x8*)(As + row * 64 + (kc ^ ((row & 7) << 3))) = v;
    }
    // stage B tile 64x64 (512 chunks)
#pragma unroll
    for (int i = 0; i < 2; ++i) {
      int c = tid + i * 256;
      int row = c >> 3, kc = (c & 7) * 8;
      bf16x8 v = *(const bf16x8*)(Bt + (size_t)(n0 + row) * Kp + k0 + kc);
      *(bf16x8*)(Bs + row * 64 + (kc ^ ((row & 7) << 3))) = v;
    }
    __syncthreads();

#pragma unroll
    for (int ks = 0; ks < 2; ++ks) {
      const int kk = ks * 32 + kq * 8;
      bf16x8 a[4], b0, b1;
      {
        int row = wn + r;
        b0 = *(const bf16x8*)(Bs + row * 64 + (kk ^ ((row & 7) << 3)));
        row = wn + 16 + r;
        b1 = *(const bf16x8*)(Bs + row * 64 + (kk ^ ((row & 7) << 3)));
      }
#pragma unroll
      for (int mi = 0; mi < 4; ++mi) {
        int row = wm + mi * 16 + r;
        a[mi] = *(const bf16x8*)(As + row * 64 + (kk ^ ((row & 7) << 3)));
      }
#pragma unroll
      for (int mi = 0; mi < 4; ++mi) {
        acc[mi][0] = __builtin_amdgcn_mfma_f32_16x16x32_bf16(a[mi], b0, acc[mi][0], 0, 0, 0);
        acc[mi][1] = __builtin_amdgcn_mfma_f32_16x16x32_bf16(a[mi], b1, acc[mi][1], 0, 0, 0);
      }
    }
    __syncthreads();
  }

  // epilogue: C[row=(lane>>4)*4+r][col=lane&15]
  const int cr = lane >> 4;
  const int cc = lane & 15;
#pragma unroll
  for (int mi = 0; mi < 4; ++mi) {
#pragma unroll
    for (int ni = 0; ni < 2; ++ni) {
      int gn = n0 + wn + ni * 16 + cc;
      if (gn >= N) continue;
      float bv = bias[gn];
#pragma unroll
      for (int rr = 0; rr < 4; ++rr) {
        int gm = m0 + wm + mi * 16 + cr * 4 + rr;
        if (gm >= M) continue;
        float vv = acc[mi][ni][rr] + bv;
        if (ACT == 1) vv = tanhf(vv);
        else if (ACT == 2) vv = 1.0f / (1.0f + expf(-vv));
        else if (ACT == 3) vv = fmaxf(vv, 0.0f);
        if (OUT_BF16) Cb[(size_t)gm * ldc + gn] = f2b(vv);
        else Cf[(size_t)gm * ldc + gn] = vv;
      }
    }
  }
}

// ---------------------------------------------------------------------------
__global__ __launch_bounds__(256) void vae_loss_partial(
    const float* __restrict__ x, const float* __restrict__ x_rec,
    float* __restrict__ partials) {
  const int n = Bn * FIN;
  float s = 0.0f;
  for (int i = blockIdx.x * blockDim.x + threadIdx.x; i < n;
       i += gridDim.x * blockDim.x) {
    float d = x[i] - x_rec[i];
    s = fmaf(d, d, s);
  }
  __shared__ float red[256];
  red[threadIdx.x] = s;
  __syncthreads();
  for (int off = 128; off >= 1; off >>= 1) {
    if (threadIdx.x < off) red[threadIdx.x] += red[threadIdx.x + off];
    __syncthreads();
  }
  if (threadIdx.x == 0) partials[blockIdx.x] = red[0];
}

// ---------------------------------------------------------------------------
__global__ __launch_bounds__(64) void csl_kernel(
    const float* __restrict__ zp, const float* __restrict__ proj,
    const int* __restrict__ pos_keys, const int* __restrict__ neg_keys,
    float* __restrict__ row_loss) {
  const int b = blockIdx.x;
  const int lane = threadIdx.x;
  const float* z = zp + (size_t)b * ZD;
  float zr[8];
#pragma unroll
  for (int j = 0; j < 8; ++j) zr[j] = z[j * 64 + lane];

  float lg[21];
  for (int t = 0; t < 21; ++t) {
    int key = (t == 0) ? pos_keys[b * 2] : neg_keys[b * DISK_N + (t - 1)];
    const float* p = proj + (size_t)key * ZD;
    float acc = 0.0f;
#pragma unroll
    for (int j = 0; j < 8; ++j) acc = fmaf(zr[j], p[j * 64 + lane], acc);
    for (int off = 32; off >= 1; off >>= 1) acc += __shfl_xor(acc, off);
    lg[t] = acc * TEMP_INV;
  }
  float m = lg[0];
#pragma unroll
  for (int t = 1; t < 21; ++t) m = fmaxf(m, lg[t]);
  float se = 0.0f;
#pragma unroll
  for (int t = 0; t < 21; ++t) se += expf(lg[t] - m);
  float loss = m + logf(se) - lg[0];
  if (lane == 0) row_loss[b] = loss;
}

// ---------------------------------------------------------------------------
__global__ __launch_bounds__(256) void finalize_kernel(
    const float* __restrict__ vae_partials, int n_vae,
    const float* __restrict__ row_loss, int n_rows, float* __restrict__ out) {
  __shared__ float red[256];
  const int tid = threadIdx.x;

  float s = 0.0f;
  for (int i = tid; i < n_vae; i += 256) s += vae_partials[i];
  red[tid] = s;
  __syncthreads();
  for (int off = 128; off >= 1; off >>= 1) {
    if (tid < off) red[tid] += red[tid + off];
    __syncthreads();
  }
  float loss_vae = red[0] * (1.0f / (float)FIN);
  __syncthreads();

  float s2 = 0.0f;
  for (int i = tid; i < n_rows; i += 256) s2 += row_loss[i];
  red[tid] = s2;
  __syncthreads();
  for (int off = 128; off >= 1; off >>= 1) {
    if (tid < off) red[tid] += red[tid + off];
    __syncthreads();
  }
  if (tid == 0) {
    out[0] = loss_vae;
    out[1] = red[0];
  }
  for (int i = tid; i < ZD; i += 256) out[2 + i] = 0.0f;
}

// ---------------------------------------------------------------------------
extern "C" void kernel_launch(void* const* d_in, const int* in_sizes, int n_in,
                              void* d_out, int out_size, void* d_ws,
                              size_t ws_size, hipStream_t stream) {
  const float* logits = (const float*)d_in[0];
  const int*   rels   = (const int*)d_in[1];
  const float* rel_emb= (const float*)d_in[2];
  const float* We1 = (const float*)d_in[3];  const float* be1 = (const float*)d_in[4];
  const float* We2 = (const float*)d_in[5];  const float* be2 = (const float*)d_in[6];
  const float* Wd1 = (const float*)d_in[7];  const float* bd1 = (const float*)d_in[8];
  const float* Wd2 = (const float*)d_in[9];  const float* bd2 = (const float*)d_in[10];
  const float* Wz1 = (const float*)d_in[11]; const float* bz1 = (const float*)d_in[12];
  const float* Wz2 = (const float*)d_in[13]; const float* bz2 = (const float*)d_in[14];
  // Wi* (15-18) are value-identical to Wk* (19-22)
  const float* Wk1 = (const float*)d_in[19]; const float* bk1 = (const float*)d_in[20];
  const float* Wk2 = (const float*)d_in[21]; const float* bk2 = (const float*)d_in[22];

  float* out = (float*)d_out;

  char* ws = (char*)d_ws;
  size_t off = 0;
  auto walloc = [&](size_t bytes) -> void* {
    void* p = ws + off;
    off = (off + bytes + 255) & ~(size_t)255;
    return p;
  };
  int*   pos_keys = (int*)walloc((size_t)Bn * 2 * sizeof(int));
  int*   neg_keys = (int*)walloc((size_t)Bn * DISK_N * sizeof(int));
  float* x        = (float*)walloc((size_t)Bn * FIN * sizeof(float));
  float* x_rec    = (float*)walloc((size_t)Bn * FIN * sizeof(float));
  float* proj     = (float*)walloc((size_t)Vn * ZD * sizeof(float));
  u16*   x_bf     = (u16*)walloc((size_t)Bn * KP_X * 2);
  u16*   t1       = (u16*)walloc((size_t)Bn * LAT * 2);
  u16*   zb       = (u16*)walloc((size_t)Bn * LAT * 2);
  u16*   t2       = (u16*)walloc((size_t)Bn * LAT * 2);
  u16*   t3       = (u16*)walloc((size_t)Bn * LAT * 2);
  u16*   th_bf    = (u16*)walloc((size_t)VP * LAT * 2);
  u16*   rel_bf   = (u16*)walloc((size_t)VP * KP_REL * 2);
  u16*   We1T     = (u16*)walloc((size_t)LAT * KP_X * 2);    // 512 x 640
  u16*   We2T     = (u16*)walloc((size_t)LAT * LAT * 2);
  u16*   Wd1T     = (u16*)walloc((size_t)LAT * LAT * 2);
  u16*   Wd2T     = (u16*)walloc((size_t)KP_X * LAT * 2);    // 640 x 512
  u16*   Wz1T     = (u16*)walloc((size_t)LAT * LAT * 2);
  u16*   Wz2T     = (u16*)walloc((size_t)LAT * LAT * 2);
  u16*   Wk1T     = (u16*)walloc((size_t)LAT * KP_REL * 2);  // 512 x 320
  u16*   Wk2T     = (u16*)walloc((size_t)LAT * LAT * 2);
  float* vae_part = (float*)walloc(1024 * sizeof(float));
  float* row_loss = (float*)walloc((size_t)Bn * sizeof(float));
  (void)ws_size; (void)in_sizes; (void)n_in; (void)out_size;

  float* zp_out = out + 2 + ZD;  // z_rel rows 1..B

  // --- weight convert+transpose (src K x N -> dst Np x Kp) ---
  TSegs segs;
  auto setseg = [&](int i, const float* s, u16* d, int K, int N, int Kp, int Np) {
    segs.s[i] = {s, d, K, N, Kp, Np, 0};
  };
  setseg(0, We1, We1T, FIN, LAT, KP_X, LAT);
  setseg(1, We2, We2T, LAT, LAT, LAT, LAT);
  setseg(2, Wd1, Wd1T, LAT, LAT, LAT, LAT);
  setseg(3, Wd2, Wd2T, LAT, FIN, LAT, KP_X);
  setseg(4, Wz1, Wz1T, LAT, LAT, LAT, LAT);
  setseg(5, Wz2, Wz2T, LAT, LAT, LAT, LAT);
  setseg(6, Wk1, Wk1T, Dn, LAT, KP_REL, LAT);
  setseg(7, Wk2, Wk2T, LAT, LAT, LAT, LAT);
  int tacc = 0;
  for (int i = 0; i < 8; ++i) {
    tacc += (segs.s[i].Np >> 6) * (segs.s[i].Kp >> 6);
    segs.s[i].tile_end = tacc;
  }

  convert_transpose_kernel<<<tacc, 256, 0, stream>>>(segs);
  convert_rel_kernel<<<1024, 256, 0, stream>>>(rel_emb, rel_bf);
  topk_kernel<<<Bn, 64, 0, stream>>>(logits, rels, pos_keys, neg_keys);
  gather_x_kernel<<<Bn, 128, 0, stream>>>(pos_keys, rel_emb, x, x_bf);

  auto grid_of = [](int M, int N) {
    return dim3((M + 127) / 128, (N + 63) / 64);
  };
  const dim3 blk(256);

  // vocab projection table: proj[v] = relu(rel_emb@Wk1+bk1)@Wk2+bk2
  gemm_mfma<3, true ><<<grid_of(Vn, LAT), blk, 0, stream>>>(rel_bf, Wk1T, bk1, nullptr, th_bf, Vn, LAT, KP_REL, LAT);
  gemm_mfma<0, false><<<grid_of(Vn, ZD ), blk, 0, stream>>>(th_bf, Wk2T, bk2, proj, nullptr, Vn, ZD, LAT, ZD);
  // encoder
  gemm_mfma<1, true ><<<grid_of(Bn, LAT), blk, 0, stream>>>(x_bf, We1T, be1, nullptr, t1, Bn, LAT, KP_X, LAT);
  gemm_mfma<1, true ><<<grid_of(Bn, ZD ), blk, 0, stream>>>(t1, We2T, be2, nullptr, zb, Bn, ZD, LAT, ZD);
  // decoder
  gemm_mfma<1, true ><<<grid_of(Bn, LAT), blk, 0, stream>>>(zb, Wd1T, bd1, nullptr, t2, Bn, LAT, ZD, LAT);
  gemm_mfma<2, false><<<grid_of(Bn, FIN), blk, 0, stream>>>(t2, Wd2T, bd2, x_rec, nullptr, Bn, FIN, LAT, FIN);
  // z_p head (straight into d_out)
  gemm_mfma<3, true ><<<grid_of(Bn, LAT), blk, 0, stream>>>(zb, Wz1T, bz1, nullptr, t3, Bn, LAT, ZD, LAT);
  gemm_mfma<0, false><<<grid_of(Bn, ZD ), blk, 0, stream>>>(t3, Wz2T, bz2, zp_out, nullptr, Bn, ZD, LAT, ZD);

  vae_loss_partial<<<1024, 256, 0, stream>>>(x, x_rec, vae_part);
  csl_kernel<<<Bn, 64, 0, stream>>>(zp_out, proj, pos_keys, neg_keys, row_loss);
  finalize_kernel<<<1, 256, 0, stream>>>(vae_part, 1024, row_loss, Bn, out);
}

// Round 4
// 148.983 us; speedup vs baseline: 4.6445x; 1.4751x over previous
//
#include <hip/hip_runtime.h>
#include <hip/hip_bf16.h>
#include <cfloat>
#include <cmath>

typedef unsigned short u16;
typedef unsigned int uint;
typedef unsigned long long u64;
typedef __attribute__((ext_vector_type(8))) short bf16x8;
typedef __attribute__((ext_vector_type(4))) float f32x4;

// Problem constants
constexpr int Bn  = 4096;
constexpr int Rn  = 1000;
constexpr int Vn  = 2000;
constexpr int Dn  = 300;
constexpr int FIN = 600;
constexpr int LAT = 512;
constexpr int ZD  = 512;
constexpr int DISK_N = 20;
constexpr float TEMP_INV = 1.0f / 0.07f;

constexpr int KP_X   = 640;  // FIN padded to 64
constexpr int KP_REL = 320;  // Dn padded
constexpr int VP     = 2048; // Vn padded

__device__ inline u16 f2b(float v) {
  __hip_bfloat16 h = __float2bfloat16(v);
  return *reinterpret_cast<u16*>(&h);
}

__device__ __forceinline__ void async_copy16(const u16* g, u16* l) {
  __builtin_amdgcn_global_load_lds(
      (const __attribute__((address_space(1))) void*)g,
      (__attribute__((address_space(3))) void*)l, 16, 0, 0);
}

// ---------------------------------------------------------------------------
// Fused top-k + gather. Block = 256 thr = 4 waves, one row per wave.
// Bottom-20 via 4-pass 8-bit radix select on sortable uint keys (exact,
// stable tie-break by index). Top-2 via packed (key, 1023-idx) max-reduce.
// Then gathers x (fp32) and x_bf (bf16, padded) for this row.
// ---------------------------------------------------------------------------
__global__ __launch_bounds__(256) void topk_gather_kernel(
    const float* __restrict__ logits, const int* __restrict__ rels,
    const float* __restrict__ rel_emb,
    int* __restrict__ pos_keys, int* __restrict__ neg_keys,
    float* __restrict__ x, u16* __restrict__ x_bf) {
  __shared__ uint hist[4][256];
  const int wv = threadIdx.x >> 6;
  const int lane = threadIdx.x & 63;
  const int row = blockIdx.x * 4 + wv;
  const float* rowp = logits + (size_t)row * Rn;

  uint s[16];
#pragma unroll
  for (int i = 0; i < 16; ++i) {
    int idx = i * 64 + lane;
    float v = (idx < Rn) ? rowp[idx] : 0.0f;
    uint u = __float_as_uint(v);
    s[i] = u ^ (uint)(((int)u >> 31) | 0x80000000);
  }
  const bool v15 = (lane < (Rn - 15 * 64));  // slot 15 validity

  // ---- radix select: find 20th smallest key T and tie-rank r ----
  uint pref = 0;
  int r = DISK_N;
#pragma unroll
  for (int pass = 0; pass < 4; ++pass) {
    const int shift = 24 - pass * 8;
    *(uint4*)&hist[wv][lane * 4] = make_uint4(0, 0, 0, 0);
    __syncthreads();
#pragma unroll
    for (int i = 0; i < 16; ++i) {
      bool valid = (i < 15) || v15;
      bool match = valid &&
          (pass == 0 || ((s[i] >> (shift + 8)) == (pref >> (shift + 8))));
      if (match) atomicAdd(&hist[wv][(s[i] >> shift) & 255], 1u);
    }
    __syncthreads();
    uint4 c = *(uint4*)&hist[wv][lane * 4];
    uint t1 = c.x + c.y, t2 = t1 + c.z, t3 = t2 + c.w;
    uint sc = t3;
#pragma unroll
    for (int off = 1; off <= 32; off <<= 1) {
      uint o = __shfl_up(sc, off);
      if (lane >= off) sc += o;
    }
    uint excl = sc - t3;
    uint i0 = excl + c.x, i1 = excl + t1, i2 = excl + t2, i3 = excl + t3;
    u64 m = __ballot(i3 >= (uint)r);
    int fl = __ffsll((unsigned long long)m) - 1;
    int j = (i0 >= (uint)r) ? 0 : (i1 >= (uint)r) ? 1 : (i2 >= (uint)r) ? 2 : 3;
    uint bexcl = (j == 0) ? excl : (j == 1) ? i0 : (j == 2) ? i1 : i2;
    int bin = lane * 4 + j;
    bin = __shfl(bin, fl);
    bexcl = __shfl(bexcl, fl);
    r -= (int)bexcl;
    pref |= (uint)bin << shift;
    __syncthreads();
  }
  const uint T = pref;

  // ---- membership: all keys < T, plus first r equals (index order) ----
  int cl = 0;
#pragma unroll
  for (int i = 0; i < 16; ++i) {
    bool valid = (i < 15) || v15;
    if (valid && s[i] < T) cl++;
  }
  uint scl = (uint)cl;
#pragma unroll
  for (int off = 1; off <= 32; off <<= 1) {
    uint o = __shfl_up(scl, off);
    if (lane >= off) scl += o;
  }
  int pos = (int)(scl - (uint)cl);
  int* nk = neg_keys + (size_t)row * DISK_N;
#pragma unroll
  for (int i = 0; i < 16; ++i) {
    bool valid = (i < 15) || v15;
    if (valid && s[i] < T) { nk[pos] = rels[(i * 64 + lane) * 2 + 1]; pos++; }
  }
  {
    int base = DISK_N - r;  // == total strictly-less count
    int need = r, taken = 0;
#pragma unroll
    for (int i = 0; i < 16; ++i) {
      if (need > 0) {
        bool valid = (i < 15) || v15;
        bool eq = valid && (s[i] == T);
        u64 mm = __ballot(eq);
        int before = __popcll(mm & ((1ull << lane) - 1ull));
        if (eq && before < need) nk[base + taken + before] = rels[(i * 64 + lane) * 2 + 1];
        int cnt = __popcll(mm);
        int take = cnt < need ? cnt : need;
        need -= take;
        taken += take;
      }
    }
  }

  // ---- top-2 (packed max; ties -> lower index) ----
  u64 b1 = 0;
#pragma unroll
  for (int i = 0; i < 16; ++i) {
    bool valid = (i < 15) || v15;
    uint k = valid ? s[i] : 0u;
    u64 p = ((u64)k << 10) | (u64)(1023 - (i * 64 + lane));
    b1 = p > b1 ? p : b1;
  }
#pragma unroll
  for (int off = 1; off < 64; off <<= 1) {
    u64 o = __shfl_xor(b1, off);
    b1 = o > b1 ? o : b1;
  }
  int idx0 = 1023 - (int)(b1 & 1023);
  u64 b2 = 0;
#pragma unroll
  for (int i = 0; i < 16; ++i) {
    int idx = i * 64 + lane;
    bool valid = ((i < 15) || v15) && (idx != idx0);
    uint k = valid ? s[i] : 0u;
    u64 p = ((u64)k << 10) | (u64)(1023 - idx);
    b2 = p > b2 ? p : b2;
  }
#pragma unroll
  for (int off = 1; off < 64; off <<= 1) {
    u64 o = __shfl_xor(b2, off);
    b2 = o > b2 ? o : b2;
  }
  int idx1 = 1023 - (int)(b2 & 1023);

  int k0 = rels[idx0 * 2 + 1];
  int k1 = rels[idx1 * 2 + 1];
  if (lane == 0) {
    pos_keys[row * 2 + 0] = k0;
    pos_keys[row * 2 + 1] = k1;
  }

  // ---- gather x / x_bf ----
  const float* e0 = rel_emb + (size_t)k0 * Dn;
  const float* e1 = rel_emb + (size_t)k1 * Dn;
  float* xb = x + (size_t)row * FIN;
  u16* xbb = x_bf + (size_t)row * KP_X;
  for (int d = lane; d < KP_X; d += 64) {
    float v = 0.0f;
    if (d < Dn) v = e0[d];
    else if (d < FIN) v = e1[d - Dn];
    if (d < FIN) xb[d] = v;
    xbb[d] = f2b(v);
  }
}

// ---------------------------------------------------------------------------
// Weight convert+transpose: src K x N fp32 -> dst Np x Kp bf16 (zero pad).
// ---------------------------------------------------------------------------
struct TSeg {
  const float* src;
  u16* dst;
  int K, N, Kp, Np;
  int tile_end;
};
struct TSegs { TSeg s[8]; };

__global__ __launch_bounds__(256) void convert_transpose_kernel(TSegs segs) {
  __shared__ float tile[64][65];
  int bid = blockIdx.x;
  int si = 0;
  while (si < 7 && bid >= segs.s[si].tile_end) ++si;
  const TSeg sg = segs.s[si];
  int t0 = (si == 0) ? 0 : segs.s[si - 1].tile_end;
  int tIdx = bid - t0;
  int tiles_k = sg.Kp >> 6;
  int tn0 = (tIdx / tiles_k) << 6;
  int tk0 = (tIdx % tiles_k) << 6;

  const int tid = threadIdx.x;
#pragma unroll
  for (int i = 0; i < 16; ++i) {
    int idx = tid + i * 256;
    int ko = idx >> 6, no = idx & 63;
    int gk = tk0 + ko, gn = tn0 + no;
    float v = 0.0f;
    if (gk < sg.K && gn < sg.N) v = sg.src[(size_t)gk * sg.N + gn];
    tile[ko][no] = v;
  }
  __syncthreads();
#pragma unroll
  for (int i = 0; i < 16; ++i) {
    int idx = tid + i * 256;
    int ko = idx & 63, no = idx >> 6;
    sg.dst[(size_t)(tn0 + no) * sg.Kp + tk0 + ko] = f2b(tile[ko][no]);
  }
}

__global__ __launch_bounds__(256) void convert_rel_kernel(
    const float* __restrict__ rel_emb, u16* __restrict__ rel_bf) {
  const int total = VP * KP_REL;
  for (int i = blockIdx.x * 256 + threadIdx.x; i < total; i += gridDim.x * 256) {
    int m = i / KP_REL, k = i - m * KP_REL;
    float v = (m < Vn && k < Dn) ? rel_emb[(size_t)m * Dn + k] : 0.0f;
    rel_bf[i] = f2b(v);
  }
}

// ---------------------------------------------------------------------------
// bf16 MFMA GEMM, 64x64 tile, 4 waves (2x2), BK=64, double-buffered
// global_load_lds staging (pre-swizzled per-lane source, linear LDS dest,
// XOR-swizzled ds_read). ACT: 0=none 1=tanh 2=sigmoid 3=relu
// ---------------------------------------------------------------------------
template <int ACT, bool OUT_BF16>
__global__ __launch_bounds__(256) void gemm_mfma(
    const u16* __restrict__ A, const u16* __restrict__ Bt,
    const float* __restrict__ bias, float* __restrict__ Cf,
    u16* __restrict__ Cb, int M, int N, int Kp, int ldc) {
  __shared__ u16 As[2][64 * 64];
  __shared__ u16 Bs[2][64 * 64];

  const int tid = threadIdx.x;
  const int lane = tid & 63;
  const int w = tid >> 6;
  const int wm = (w >> 1) * 32;
  const int wn = (w & 1) * 32;
  const int m0 = blockIdx.x * 64;
  const int n0 = blockIdx.y * 64;

  // staging addresses: lane covers row (lane>>3) of an 8-row group, and the
  // inverse-swizzled column chunk so LDS[row][c] = global[row][c ^ (row&7)]
  const int rA = lane >> 3;
  const int cC = ((lane & 7) ^ rA) * 8;
  const u16* gA = A + (size_t)(m0 + w * 16 + rA) * Kp + cC;
  const u16* gB = Bt + (size_t)(n0 + w * 16 + rA) * Kp + cC;

  auto stage = [&](int buf, int k0) {
#pragma unroll
    for (int j = 0; j < 2; ++j) {
      async_copy16(gA + (size_t)j * 8 * Kp + k0, &As[buf][(w * 16 + j * 8) * 64]);
      async_copy16(gB + (size_t)j * 8 * Kp + k0, &Bs[buf][(w * 16 + j * 8) * 64]);
    }
  };

  f32x4 acc[2][2];
#pragma unroll
  for (int i = 0; i < 2; ++i)
#pragma unroll
    for (int j = 0; j < 2; ++j) acc[i][j] = (f32x4)(0.0f);

  const int r = lane & 15;
  const int kq = lane >> 4;

  const int NT = Kp >> 6;
  stage(0, 0);
  __syncthreads();
  int cur = 0;
  for (int t = 0; t < NT; ++t) {
    if (t + 1 < NT) stage(cur ^ 1, (t + 1) << 6);
#pragma unroll
    for (int ks = 0; ks < 2; ++ks) {
      const int kk = ks * 32 + kq * 8;
      const int xm = (r & 7) << 3;
      bf16x8 a0 = *(const bf16x8*)(&As[cur][(wm + r) * 64 + (kk ^ xm)]);
      bf16x8 a1 = *(const bf16x8*)(&As[cur][(wm + 16 + r) * 64 + (kk ^ xm)]);
      bf16x8 b0 = *(const bf16x8*)(&Bs[cur][(wn + r) * 64 + (kk ^ xm)]);
      bf16x8 b1 = *(const bf16x8*)(&Bs[cur][(wn + 16 + r) * 64 + (kk ^ xm)]);
      acc[0][0] = __builtin_amdgcn_mfma_f32_16x16x32_bf16(a0, b0, acc[0][0], 0, 0, 0);
      acc[0][1] = __builtin_amdgcn_mfma_f32_16x16x32_bf16(a0, b1, acc[0][1], 0, 0, 0);
      acc[1][0] = __builtin_amdgcn_mfma_f32_16x16x32_bf16(a1, b0, acc[1][0], 0, 0, 0);
      acc[1][1] = __builtin_amdgcn_mfma_f32_16x16x32_bf16(a1, b1, acc[1][1], 0, 0, 0);
    }
    __syncthreads();
    cur ^= 1;
  }

  const int cr = lane >> 4;
  const int cc = lane & 15;
#pragma unroll
  for (int mi = 0; mi < 2; ++mi) {
#pragma unroll
    for (int ni = 0; ni < 2; ++ni) {
      int gn = n0 + wn + ni * 16 + cc;
      if (gn >= N) continue;
      float bv = bias[gn];
#pragma unroll
      for (int rr = 0; rr < 4; ++rr) {
        int gm = m0 + wm + mi * 16 + cr * 4 + rr;
        if (gm >= M) continue;
        float vv = acc[mi][ni][rr] + bv;
        if (ACT == 1) vv = tanhf(vv);
        else if (ACT == 2) vv = 1.0f / (1.0f + expf(-vv));
        else if (ACT == 3) vv = fmaxf(vv, 0.0f);
        if (OUT_BF16) Cb[(size_t)gm * ldc + gn] = f2b(vv);
        else Cf[(size_t)gm * ldc + gn] = vv;
      }
    }
  }
}

// ---------------------------------------------------------------------------
__global__ __launch_bounds__(256) void vae_loss_partial(
    const float* __restrict__ x, const float* __restrict__ x_rec,
    float* __restrict__ partials) {
  const int n = Bn * FIN;
  float s = 0.0f;
  for (int i = blockIdx.x * blockDim.x + threadIdx.x; i < n;
       i += gridDim.x * blockDim.x) {
    float d = x[i] - x_rec[i];
    s = fmaf(d, d, s);
  }
  __shared__ float red[256];
  red[threadIdx.x] = s;
  __syncthreads();
  for (int off = 128; off >= 1; off >>= 1) {
    if (threadIdx.x < off) red[threadIdx.x] += red[threadIdx.x + off];
    __syncthreads();
  }
  if (threadIdx.x == 0) partials[blockIdx.x] = red[0];
}

// ---------------------------------------------------------------------------
__global__ __launch_bounds__(64) void csl_kernel(
    const float* __restrict__ zp, const float* __restrict__ proj,
    const int* __restrict__ pos_keys, const int* __restrict__ neg_keys,
    float* __restrict__ row_loss) {
  const int b = blockIdx.x;
  const int lane = threadIdx.x;
  const float* z = zp + (size_t)b * ZD;
  float zr[8];
#pragma unroll
  for (int j = 0; j < 8; ++j) zr[j] = z[j * 64 + lane];

  float lg[21];
  for (int t = 0; t < 21; ++t) {
    int key = (t == 0) ? pos_keys[b * 2] : neg_keys[b * DISK_N + (t - 1)];
    const float* p = proj + (size_t)key * ZD;
    float acc = 0.0f;
#pragma unroll
    for (int j = 0; j < 8; ++j) acc = fmaf(zr[j], p[j * 64 + lane], acc);
    for (int off = 32; off >= 1; off >>= 1) acc += __shfl_xor(acc, off);
    lg[t] = acc * TEMP_INV;
  }
  float m = lg[0];
#pragma unroll
  for (int t = 1; t < 21; ++t) m = fmaxf(m, lg[t]);
  float se = 0.0f;
#pragma unroll
  for (int t = 0; t < 21; ++t) se += expf(lg[t] - m);
  float loss = m + logf(se) - lg[0];
  if (lane == 0) row_loss[b] = loss;
}

// ---------------------------------------------------------------------------
__global__ __launch_bounds__(256) void finalize_kernel(
    const float* __restrict__ vae_partials, int n_vae,
    const float* __restrict__ row_loss, int n_rows, float* __restrict__ out) {
  __shared__ float red[256];
  const int tid = threadIdx.x;

  float s = 0.0f;
  for (int i = tid; i < n_vae; i += 256) s += vae_partials[i];
  red[tid] = s;
  __syncthreads();
  for (int off = 128; off >= 1; off >>= 1) {
    if (tid < off) red[tid] += red[tid + off];
    __syncthreads();
  }
  float loss_vae = red[0] * (1.0f / (float)FIN);
  __syncthreads();

  float s2 = 0.0f;
  for (int i = tid; i < n_rows; i += 256) s2 += row_loss[i];
  red[tid] = s2;
  __syncthreads();
  for (int off = 128; off >= 1; off >>= 1) {
    if (tid < off) red[tid] += red[tid + off];
    __syncthreads();
  }
  if (tid == 0) {
    out[0] = loss_vae;
    out[1] = red[0];
  }
  for (int i = tid; i < ZD; i += 256) out[2 + i] = 0.0f;
}

// ---------------------------------------------------------------------------
extern "C" void kernel_launch(void* const* d_in, const int* in_sizes, int n_in,
                              void* d_out, int out_size, void* d_ws,
                              size_t ws_size, hipStream_t stream) {
  const float* logits = (const float*)d_in[0];
  const int*   rels   = (const int*)d_in[1];
  const float* rel_emb= (const float*)d_in[2];
  const float* We1 = (const float*)d_in[3];  const float* be1 = (const float*)d_in[4];
  const float* We2 = (const float*)d_in[5];  const float* be2 = (const float*)d_in[6];
  const float* Wd1 = (const float*)d_in[7];  const float* bd1 = (const float*)d_in[8];
  const float* Wd2 = (const float*)d_in[9];  const float* bd2 = (const float*)d_in[10];
  const float* Wz1 = (const float*)d_in[11]; const float* bz1 = (const float*)d_in[12];
  const float* Wz2 = (const float*)d_in[13]; const float* bz2 = (const float*)d_in[14];
  const float* Wk1 = (const float*)d_in[19]; const float* bk1 = (const float*)d_in[20];
  const float* Wk2 = (const float*)d_in[21]; const float* bk2 = (const float*)d_in[22];

  float* out = (float*)d_out;

  char* ws = (char*)d_ws;
  size_t off = 0;
  auto walloc = [&](size_t bytes) -> void* {
    void* p = ws + off;
    off = (off + bytes + 255) & ~(size_t)255;
    return p;
  };
  int*   pos_keys = (int*)walloc((size_t)Bn * 2 * sizeof(int));
  int*   neg_keys = (int*)walloc((size_t)Bn * DISK_N * sizeof(int));
  float* x        = (float*)walloc((size_t)Bn * FIN * sizeof(float));
  float* x_rec    = (float*)walloc((size_t)Bn * FIN * sizeof(float));
  float* proj     = (float*)walloc((size_t)Vn * ZD * sizeof(float));
  u16*   x_bf     = (u16*)walloc((size_t)Bn * KP_X * 2);
  u16*   t1       = (u16*)walloc((size_t)Bn * LAT * 2);
  u16*   zb       = (u16*)walloc((size_t)Bn * LAT * 2);
  u16*   t2       = (u16*)walloc((size_t)Bn * LAT * 2);
  u16*   t3       = (u16*)walloc((size_t)Bn * LAT * 2);
  u16*   th_bf    = (u16*)walloc((size_t)VP * LAT * 2);
  u16*   rel_bf   = (u16*)walloc((size_t)VP * KP_REL * 2);
  u16*   We1T     = (u16*)walloc((size_t)LAT * KP_X * 2);
  u16*   We2T     = (u16*)walloc((size_t)LAT * LAT * 2);
  u16*   Wd1T     = (u16*)walloc((size_t)LAT * LAT * 2);
  u16*   Wd2T     = (u16*)walloc((size_t)KP_X * LAT * 2);
  u16*   Wz1T     = (u16*)walloc((size_t)LAT * LAT * 2);
  u16*   Wz2T     = (u16*)walloc((size_t)LAT * LAT * 2);
  u16*   Wk1T     = (u16*)walloc((size_t)LAT * KP_REL * 2);
  u16*   Wk2T     = (u16*)walloc((size_t)LAT * LAT * 2);
  float* vae_part = (float*)walloc(1024 * sizeof(float));
  float* row_loss = (float*)walloc((size_t)Bn * sizeof(float));
  (void)ws_size; (void)in_sizes; (void)n_in; (void)out_size;

  float* zp_out = out + 2 + ZD;

  TSegs segs;
  auto setseg = [&](int i, const float* s, u16* d, int K, int N, int Kp, int Np) {
    segs.s[i] = {s, d, K, N, Kp, Np, 0};
  };
  setseg(0, We1, We1T, FIN, LAT, KP_X, LAT);
  setseg(1, We2, We2T, LAT, LAT, LAT, LAT);
  setseg(2, Wd1, Wd1T, LAT, LAT, LAT, LAT);
  setseg(3, Wd2, Wd2T, LAT, FIN, LAT, KP_X);
  setseg(4, Wz1, Wz1T, LAT, LAT, LAT, LAT);
  setseg(5, Wz2, Wz2T, LAT, LAT, LAT, LAT);
  setseg(6, Wk1, Wk1T, Dn, LAT, KP_REL, LAT);
  setseg(7, Wk2, Wk2T, LAT, LAT, LAT, LAT);
  int tacc = 0;
  for (int i = 0; i < 8; ++i) {
    tacc += (segs.s[i].Np >> 6) * (segs.s[i].Kp >> 6);
    segs.s[i].tile_end = tacc;
  }

  convert_transpose_kernel<<<tacc, 256, 0, stream>>>(segs);
  convert_rel_kernel<<<1024, 256, 0, stream>>>(rel_emb, rel_bf);
  topk_gather_kernel<<<Bn / 4, 256, 0, stream>>>(logits, rels, rel_emb,
                                                 pos_keys, neg_keys, x, x_bf);

  auto grid_of = [](int M, int N) {
    return dim3((M + 63) / 64, (N + 63) / 64);
  };
  const dim3 blk(256);

  // vocab projection table
  gemm_mfma<3, true ><<<grid_of(Vn, LAT), blk, 0, stream>>>(rel_bf, Wk1T, bk1, nullptr, th_bf, Vn, LAT, KP_REL, LAT);
  gemm_mfma<0, false><<<grid_of(Vn, ZD ), blk, 0, stream>>>(th_bf, Wk2T, bk2, proj, nullptr, Vn, ZD, LAT, ZD);
  // encoder
  gemm_mfma<1, true ><<<grid_of(Bn, LAT), blk, 0, stream>>>(x_bf, We1T, be1, nullptr, t1, Bn, LAT, KP_X, LAT);
  gemm_mfma<1, true ><<<grid_of(Bn, ZD ), blk, 0, stream>>>(t1, We2T, be2, nullptr, zb, Bn, ZD, LAT, ZD);
  // decoder
  gemm_mfma<1, true ><<<grid_of(Bn, LAT), blk, 0, stream>>>(zb, Wd1T, bd1, nullptr, t2, Bn, LAT, ZD, LAT);
  gemm_mfma<2, false><<<grid_of(Bn, FIN), blk, 0, stream>>>(t2, Wd2T, bd2, x_rec, nullptr, Bn, FIN, LAT, FIN);
  // z_p head
  gemm_mfma<3, true ><<<grid_of(Bn, LAT), blk, 0, stream>>>(zb, Wz1T, bz1, nullptr, t3, Bn, LAT, ZD, LAT);
  gemm_mfma<0, false><<<grid_of(Bn, ZD ), blk, 0, stream>>>(t3, Wz2T, bz2, zp_out, nullptr, Bn, ZD, LAT, ZD);

  vae_loss_partial<<<1024, 256, 0, stream>>>(x, x_rec, vae_part);
  csl_kernel<<<Bn, 64, 0, stream>>>(zp_out, proj, pos_keys, neg_keys, row_loss);
  finalize_kernel<<<1, 256, 0, stream>>>(vae_part, 1024, row_loss, Bn, out);
}

// Round 5
// 116.609 us; speedup vs baseline: 5.9340x; 1.2776x over previous
//
#include <hip/hip_runtime.h>
#include <hip/hip_bf16.h>
#include <cfloat>
#include <cmath>

typedef unsigned short u16;
typedef unsigned int uint;
typedef unsigned long long u64;
typedef __attribute__((ext_vector_type(8))) short bf16x8;
typedef __attribute__((ext_vector_type(4))) float f32x4;

// Problem constants
constexpr int Bn  = 4096;
constexpr int Rn  = 1000;
constexpr int Vn  = 2000;
constexpr int Dn  = 300;
constexpr int FIN = 600;
constexpr int LAT = 512;
constexpr int ZD  = 512;
constexpr int DISK_N = 20;
constexpr float TEMP_INV = 1.0f / 0.07f;

constexpr int KP_X   = 640;  // FIN padded to 64
constexpr int KP_REL = 320;  // Dn padded
constexpr int VP     = 2048; // Vn padded

__device__ inline u16 f2b(float v) {
  __hip_bfloat16 h = __float2bfloat16(v);
  return *reinterpret_cast<u16*>(&h);
}
__device__ inline float b2f(u16 u) {
  return __uint_as_float((uint)u << 16);
}

__device__ __forceinline__ void async_copy16(const u16* g, u16* l) {
  __builtin_amdgcn_global_load_lds(
      (const __attribute__((address_space(1))) void*)g,
      (__attribute__((address_space(3))) void*)l, 16, 0, 0);
}

// ===========================================================================
// PREP kernel: blocks [0, conv_tiles) do weight transpose-convert / rel pad;
// blocks [conv_tiles, conv_tiles+Bn/4) do topk+gather (4 rows per block).
// ===========================================================================
struct TSeg {
  const float* src;
  u16* dst;
  int K, N, Kp;   // mode0: src K x N, dst N' x Kp (transpose). mode1: src K x N rows/cols, dst stride Kp
  int mode;       // 0 = transpose+convert, 1 = pad+convert (no transpose)
  int tile_end;   // exclusive prefix over conv tiles
};
struct TSegs9 { TSeg s[9]; };

__global__ __launch_bounds__(256) void prep_kernel(
    TSegs9 segs, int conv_tiles,
    const float* __restrict__ logits, const int* __restrict__ rels,
    const float* __restrict__ rel_emb,
    int* __restrict__ pos_keys, int* __restrict__ neg_keys,
    u16* __restrict__ x_bf) {
  __shared__ float tile[64][65];
  const int tid = threadIdx.x;
  const int bid = blockIdx.x;

  if (bid < conv_tiles) {
    int si = 0;
    while (si < 8 && bid >= segs.s[si].tile_end) ++si;
    const TSeg sg = segs.s[si];
    int t0 = (si == 0) ? 0 : segs.s[si - 1].tile_end;
    int t = bid - t0;
    int tiles_k = sg.Kp >> 6;
    int tr0 = (t / tiles_k) << 6;  // dst row block (mode0: n; mode1: src row)
    int tk0 = (t % tiles_k) << 6;  // dst col block (k)

    if (sg.mode == 0) {
      // transpose: dst[n][k] = src[k][n]
#pragma unroll
      for (int i = 0; i < 16; ++i) {
        int idx = tid + i * 256;
        int ko = idx >> 6, no = idx & 63;
        int gk = tk0 + ko, gn = tr0 + no;
        float v = 0.0f;
        if (gk < sg.K && gn < sg.N) v = sg.src[(size_t)gk * sg.N + gn];
        tile[ko][no] = v;
      }
      __syncthreads();
#pragma unroll
      for (int i = 0; i < 16; ++i) {
        int idx = tid + i * 256;
        int ko = idx & 63, no = idx >> 6;
        sg.dst[(size_t)(tr0 + no) * sg.Kp + tk0 + ko] = f2b(tile[ko][no]);
      }
    } else {
      // pad-convert: dst[m][k] = src[m][k], zero pad (src K rows x N cols)
#pragma unroll
      for (int i = 0; i < 16; ++i) {
        int idx = tid + i * 256;
        int mo = idx >> 6, ko = idx & 63;
        int gm = tr0 + mo, gk = tk0 + ko;
        float v = 0.0f;
        if (gm < sg.K && gk < sg.N) v = sg.src[(size_t)gm * sg.N + gk];
        sg.dst[(size_t)gm * sg.Kp + gk] = f2b(v);
      }
    }
    return;
  }

  // ---------------- topk + gather: 4 rows per block, one per wave ---------
  uint (*hist)[256] = reinterpret_cast<uint (*)[256]>(&tile[0][0]);
  const int wv = tid >> 6;
  const int lane = tid & 63;
  const int row = (bid - conv_tiles) * 4 + wv;
  const float* rowp = logits + (size_t)row * Rn;

  uint s[16];
#pragma unroll
  for (int i = 0; i < 16; ++i) {
    int idx = i * 64 + lane;
    float v = (idx < Rn) ? rowp[idx] : 0.0f;
    uint u = __float_as_uint(v);
    s[i] = u ^ (uint)(((int)u >> 31) | 0x80000000);
  }
  const bool v15 = (lane < (Rn - 15 * 64));

  // radix select: 20th smallest key T, tie-rank r
  uint pref = 0;
  int r = DISK_N;
#pragma unroll
  for (int pass = 0; pass < 4; ++pass) {
    const int shift = 24 - pass * 8;
    *(uint4*)&hist[wv][lane * 4] = make_uint4(0, 0, 0, 0);
    __syncthreads();
#pragma unroll
    for (int i = 0; i < 16; ++i) {
      bool valid = (i < 15) || v15;
      bool match = valid &&
          (pass == 0 || ((s[i] >> (shift + 8)) == (pref >> (shift + 8))));
      if (match) atomicAdd(&hist[wv][(s[i] >> shift) & 255], 1u);
    }
    __syncthreads();
    uint4 c = *(uint4*)&hist[wv][lane * 4];
    uint t1 = c.x + c.y, t2 = t1 + c.z, t3 = t2 + c.w;
    uint sc = t3;
#pragma unroll
    for (int off = 1; off <= 32; off <<= 1) {
      uint o = __shfl_up(sc, off);
      if (lane >= off) sc += o;
    }
    uint excl = sc - t3;
    uint i0 = excl + c.x, i1 = excl + t1, i2 = excl + t2, i3 = excl + t3;
    u64 m = __ballot(i3 >= (uint)r);
    int fl = __ffsll((unsigned long long)m) - 1;
    int j = (i0 >= (uint)r) ? 0 : (i1 >= (uint)r) ? 1 : (i2 >= (uint)r) ? 2 : 3;
    uint bexcl = (j == 0) ? excl : (j == 1) ? i0 : (j == 2) ? i1 : i2;
    int bin = lane * 4 + j;
    bin = __shfl(bin, fl);
    bexcl = __shfl(bexcl, fl);
    r -= (int)bexcl;
    pref |= (uint)bin << shift;
    __syncthreads();
  }
  const uint T = pref;

  // membership: all < T, plus first r equals (index order)
  int cl = 0;
#pragma unroll
  for (int i = 0; i < 16; ++i) {
    bool valid = (i < 15) || v15;
    if (valid && s[i] < T) cl++;
  }
  uint scl = (uint)cl;
#pragma unroll
  for (int off = 1; off <= 32; off <<= 1) {
    uint o = __shfl_up(scl, off);
    if (lane >= off) scl += o;
  }
  int pos = (int)(scl - (uint)cl);
  int* nk = neg_keys + (size_t)row * DISK_N;
#pragma unroll
  for (int i = 0; i < 16; ++i) {
    bool valid = (i < 15) || v15;
    if (valid && s[i] < T) { nk[pos] = rels[(i * 64 + lane) * 2 + 1]; pos++; }
  }
  {
    int base = DISK_N - r;
    int need = r, taken = 0;
#pragma unroll
    for (int i = 0; i < 16; ++i) {
      if (need > 0) {
        bool valid = (i < 15) || v15;
        bool eq = valid && (s[i] == T);
        u64 mm = __ballot(eq);
        int before = __popcll(mm & ((1ull << lane) - 1ull));
        if (eq && before < need) nk[base + taken + before] = rels[(i * 64 + lane) * 2 + 1];
        int cnt = __popcll(mm);
        int take = cnt < need ? cnt : need;
        need -= take;
        taken += take;
      }
    }
  }

  // top-2 (packed max; ties -> lower index)
  u64 b1 = 0;
#pragma unroll
  for (int i = 0; i < 16; ++i) {
    bool valid = (i < 15) || v15;
    uint k = valid ? s[i] : 0u;
    u64 p = ((u64)k << 10) | (u64)(1023 - (i * 64 + lane));
    b1 = p > b1 ? p : b1;
  }
#pragma unroll
  for (int off = 1; off < 64; off <<= 1) {
    u64 o = __shfl_xor(b1, off);
    b1 = o > b1 ? o : b1;
  }
  int idx0 = 1023 - (int)(b1 & 1023);
  u64 b2 = 0;
#pragma unroll
  for (int i = 0; i < 16; ++i) {
    int idx = i * 64 + lane;
    bool valid = ((i < 15) || v15) && (idx != idx0);
    uint k = valid ? s[i] : 0u;
    u64 p = ((u64)k << 10) | (u64)(1023 - idx);
    b2 = p > b2 ? p : b2;
  }
#pragma unroll
  for (int off = 1; off < 64; off <<= 1) {
    u64 o = __shfl_xor(b2, off);
    b2 = o > b2 ? o : b2;
  }
  int idx1 = 1023 - (int)(b2 & 1023);

  int k0 = rels[idx0 * 2 + 1];
  int k1 = rels[idx1 * 2 + 1];
  if (lane == 0) {
    pos_keys[row * 2 + 0] = k0;
    pos_keys[row * 2 + 1] = k1;
  }

  const float* e0 = rel_emb + (size_t)k0 * Dn;
  const float* e1 = rel_emb + (size_t)k1 * Dn;
  u16* xbb = x_bf + (size_t)row * KP_X;
  for (int d = lane; d < KP_X; d += 64) {
    float v = 0.0f;
    if (d < Dn) v = e0[d];
    else if (d < FIN) v = e1[d - Dn];
    xbb[d] = f2b(v);
  }
}

// ===========================================================================
// Segmented bf16 MFMA GEMM: up to 2 segments per launch, 64x64 tiles,
// 4 waves, BK=64, double-buffered global_load_lds (pre-swizzled source,
// linear LDS dest, XOR ds_read). Optional fused VAE-loss epilogue.
// act: 0=none 1=tanh 2=sigmoid 3=relu
// ===========================================================================
struct GSeg {
  const u16* A;       // M' x Kp (row-padded to tile mult)
  const u16* Bt;      // N' x Kp
  const float* bias;  // N
  float* Cf;          // fp32 out (or null)
  u16* Cb;            // bf16 out (or null)
  const u16* xref;    // vae: bf16 reference, stride ldc
  float* part;        // vae: per-tile partials (non-null enables vae mode)
  int M, N, Kp, ldc, act, tiles_n, tile_end;
};
struct GSegs2 { GSeg s[2]; };

__global__ __launch_bounds__(256) void gemm_multi(GSegs2 segs) {
  __shared__ u16 As[2][64 * 64];
  __shared__ u16 Bs[2][64 * 64];

  const int tid = threadIdx.x;
  const int lane = tid & 63;
  const int w = tid >> 6;
  const int wm = (w >> 1) * 32;
  const int wn = (w & 1) * 32;

  const int bid = blockIdx.x;
  const int si = (bid >= segs.s[0].tile_end) ? 1 : 0;
  const GSeg sg = segs.s[si];
  const int t = bid - (si ? segs.s[0].tile_end : 0);
  const int m0 = (t / sg.tiles_n) * 64;
  const int n0 = (t % sg.tiles_n) * 64;
  const int Kp = sg.Kp;

  const int rA = lane >> 3;
  const int cC = ((lane & 7) ^ rA) * 8;
  const u16* gA = sg.A + (size_t)(m0 + w * 16 + rA) * Kp + cC;
  const u16* gB = sg.Bt + (size_t)(n0 + w * 16 + rA) * Kp + cC;

  auto stage = [&](int buf, int k0) {
#pragma unroll
    for (int j = 0; j < 2; ++j) {
      async_copy16(gA + (size_t)j * 8 * Kp + k0, &As[buf][(w * 16 + j * 8) * 64]);
      async_copy16(gB + (size_t)j * 8 * Kp + k0, &Bs[buf][(w * 16 + j * 8) * 64]);
    }
  };

  f32x4 acc[2][2];
#pragma unroll
  for (int i = 0; i < 2; ++i)
#pragma unroll
    for (int j = 0; j < 2; ++j) acc[i][j] = (f32x4)(0.0f);

  const int r = lane & 15;
  const int kq = lane >> 4;

  const int NT = Kp >> 6;
  stage(0, 0);
  __syncthreads();
  int cur = 0;
  for (int tt = 0; tt < NT; ++tt) {
    if (tt + 1 < NT) stage(cur ^ 1, (tt + 1) << 6);
#pragma unroll
    for (int ks = 0; ks < 2; ++ks) {
      const int kk = ks * 32 + kq * 8;
      const int xm = (r & 7) << 3;
      bf16x8 a0 = *(const bf16x8*)(&As[cur][(wm + r) * 64 + (kk ^ xm)]);
      bf16x8 a1 = *(const bf16x8*)(&As[cur][(wm + 16 + r) * 64 + (kk ^ xm)]);
      bf16x8 b0 = *(const bf16x8*)(&Bs[cur][(wn + r) * 64 + (kk ^ xm)]);
      bf16x8 b1 = *(const bf16x8*)(&Bs[cur][(wn + 16 + r) * 64 + (kk ^ xm)]);
      acc[0][0] = __builtin_amdgcn_mfma_f32_16x16x32_bf16(a0, b0, acc[0][0], 0, 0, 0);
      acc[0][1] = __builtin_amdgcn_mfma_f32_16x16x32_bf16(a0, b1, acc[0][1], 0, 0, 0);
      acc[1][0] = __builtin_amdgcn_mfma_f32_16x16x32_bf16(a1, b0, acc[1][0], 0, 0, 0);
      acc[1][1] = __builtin_amdgcn_mfma_f32_16x16x32_bf16(a1, b1, acc[1][1], 0, 0, 0);
    }
    __syncthreads();
    cur ^= 1;
  }

  const int cr = lane >> 4;
  const int cc = lane & 15;
  const bool fuse_vae = (sg.part != nullptr);
  float vsum = 0.0f;
#pragma unroll
  for (int mi = 0; mi < 2; ++mi) {
#pragma unroll
    for (int ni = 0; ni < 2; ++ni) {
      int gn = n0 + wn + ni * 16 + cc;
      if (gn >= sg.N) continue;
      float bv = sg.bias[gn];
#pragma unroll
      for (int rr = 0; rr < 4; ++rr) {
        int gm = m0 + wm + mi * 16 + cr * 4 + rr;
        if (gm >= sg.M) continue;
        float vv = acc[mi][ni][rr] + bv;
        if (sg.act == 1) vv = tanhf(vv);
        else if (sg.act == 2) vv = 1.0f / (1.0f + expf(-vv));
        else if (sg.act == 3) vv = fmaxf(vv, 0.0f);
        if (fuse_vae) {
          float xr = b2f(sg.xref[(size_t)gm * sg.ldc + gn]);
          float d = xr - vv;
          vsum = fmaf(d, d, vsum);
        } else if (sg.Cb) {
          sg.Cb[(size_t)gm * sg.ldc + gn] = f2b(vv);
        } else {
          sg.Cf[(size_t)gm * sg.ldc + gn] = vv;
        }
      }
    }
  }
  if (fuse_vae) {
    float* red = (float*)&As[0][0];
    red[tid] = vsum;
    __syncthreads();
    for (int off = 128; off >= 1; off >>= 1) {
      if (tid < off) red[tid] += red[tid + off];
      __syncthreads();
    }
    if (tid == 0) sg.part[t] = red[0];
  }
}

// ---------------------------------------------------------------------------
// Contrastive loss: 4 rows per block (one per wave).
// ---------------------------------------------------------------------------
__global__ __launch_bounds__(256) void csl_kernel(
    const float* __restrict__ zp, const float* __restrict__ proj,
    const int* __restrict__ pos_keys, const int* __restrict__ neg_keys,
    float* __restrict__ row_loss) {
  const int wv = threadIdx.x >> 6;
  const int lane = threadIdx.x & 63;
  const int b = blockIdx.x * 4 + wv;
  const float* z = zp + (size_t)b * ZD;
  float zr[8];
#pragma unroll
  for (int j = 0; j < 8; ++j) zr[j] = z[j * 64 + lane];

  float lg[21];
  for (int t = 0; t < 21; ++t) {
    int key = (t == 0) ? pos_keys[b * 2] : neg_keys[b * DISK_N + (t - 1)];
    const float* p = proj + (size_t)key * ZD;
    float acc = 0.0f;
#pragma unroll
    for (int j = 0; j < 8; ++j) acc = fmaf(zr[j], p[j * 64 + lane], acc);
    for (int off = 32; off >= 1; off >>= 1) acc += __shfl_xor(acc, off);
    lg[t] = acc * TEMP_INV;
  }
  float m = lg[0];
#pragma unroll
  for (int t = 1; t < 21; ++t) m = fmaxf(m, lg[t]);
  float se = 0.0f;
#pragma unroll
  for (int t = 0; t < 21; ++t) se += expf(lg[t] - m);
  float loss = m + logf(se) - lg[0];
  if (lane == 0) row_loss[b] = loss;
}

// ---------------------------------------------------------------------------
__global__ __launch_bounds__(256) void finalize_kernel(
    const float* __restrict__ vae_partials, int n_vae,
    const float* __restrict__ row_loss, int n_rows, float* __restrict__ out) {
  __shared__ float red[256];
  const int tid = threadIdx.x;

  float s = 0.0f;
  for (int i = tid; i < n_vae; i += 256) s += vae_partials[i];
  red[tid] = s;
  __syncthreads();
  for (int off = 128; off >= 1; off >>= 1) {
    if (tid < off) red[tid] += red[tid + off];
    __syncthreads();
  }
  float loss_vae = red[0] * (1.0f / (float)FIN);
  __syncthreads();

  float s2 = 0.0f;
  for (int i = tid; i < n_rows; i += 256) s2 += row_loss[i];
  red[tid] = s2;
  __syncthreads();
  for (int off = 128; off >= 1; off >>= 1) {
    if (tid < off) red[tid] += red[tid + off];
    __syncthreads();
  }
  if (tid == 0) {
    out[0] = loss_vae;
    out[1] = red[0];
  }
  for (int i = tid; i < ZD; i += 256) out[2 + i] = 0.0f;
}

// ---------------------------------------------------------------------------
extern "C" void kernel_launch(void* const* d_in, const int* in_sizes, int n_in,
                              void* d_out, int out_size, void* d_ws,
                              size_t ws_size, hipStream_t stream) {
  const float* logits = (const float*)d_in[0];
  const int*   rels   = (const int*)d_in[1];
  const float* rel_emb= (const float*)d_in[2];
  const float* We1 = (const float*)d_in[3];  const float* be1 = (const float*)d_in[4];
  const float* We2 = (const float*)d_in[5];  const float* be2 = (const float*)d_in[6];
  const float* Wd1 = (const float*)d_in[7];  const float* bd1 = (const float*)d_in[8];
  const float* Wd2 = (const float*)d_in[9];  const float* bd2 = (const float*)d_in[10];
  const float* Wz1 = (const float*)d_in[11]; const float* bz1 = (const float*)d_in[12];
  const float* Wz2 = (const float*)d_in[13]; const float* bz2 = (const float*)d_in[14];
  const float* Wk1 = (const float*)d_in[19]; const float* bk1 = (const float*)d_in[20];
  const float* Wk2 = (const float*)d_in[21]; const float* bk2 = (const float*)d_in[22];

  float* out = (float*)d_out;

  char* ws = (char*)d_ws;
  size_t off = 0;
  auto walloc = [&](size_t bytes) -> void* {
    void* p = ws + off;
    off = (off + bytes + 255) & ~(size_t)255;
    return p;
  };
  int*   pos_keys = (int*)walloc((size_t)Bn * 2 * sizeof(int));
  int*   neg_keys = (int*)walloc((size_t)Bn * DISK_N * sizeof(int));
  float* proj     = (float*)walloc((size_t)Vn * ZD * sizeof(float));
  u16*   x_bf     = (u16*)walloc((size_t)Bn * KP_X * 2);
  u16*   t1       = (u16*)walloc((size_t)Bn * LAT * 2);
  u16*   zb       = (u16*)walloc((size_t)Bn * LAT * 2);
  u16*   t2       = (u16*)walloc((size_t)Bn * LAT * 2);
  u16*   t3       = (u16*)walloc((size_t)Bn * LAT * 2);
  u16*   th_bf    = (u16*)walloc((size_t)VP * LAT * 2);
  u16*   rel_bf   = (u16*)walloc((size_t)VP * KP_REL * 2);
  u16*   We1T     = (u16*)walloc((size_t)LAT * KP_X * 2);
  u16*   We2T     = (u16*)walloc((size_t)LAT * LAT * 2);
  u16*   Wd1T     = (u16*)walloc((size_t)LAT * LAT * 2);
  u16*   Wd2T     = (u16*)walloc((size_t)KP_X * LAT * 2);
  u16*   Wz1T     = (u16*)walloc((size_t)LAT * LAT * 2);
  u16*   Wz2T     = (u16*)walloc((size_t)LAT * LAT * 2);
  u16*   Wk1T     = (u16*)walloc((size_t)LAT * KP_REL * 2);
  u16*   Wk2T     = (u16*)walloc((size_t)LAT * LAT * 2);
  float* vae_part = (float*)walloc(1024 * sizeof(float));
  float* row_loss = (float*)walloc((size_t)Bn * sizeof(float));
  (void)ws_size; (void)in_sizes; (void)n_in; (void)out_size;

  float* zp_out = out + 2 + ZD;

  // ---- prep: weight transposes + rel pad + topk/gather in one launch ----
  TSegs9 segs;
  auto setseg = [&](int i, const float* s, u16* d, int K, int N, int Kp, int mode) {
    segs.s[i] = {s, d, K, N, Kp, mode, 0};
  };
  setseg(0, We1, We1T, FIN, LAT, KP_X, 0);
  setseg(1, We2, We2T, LAT, LAT, LAT, 0);
  setseg(2, Wd1, Wd1T, LAT, LAT, LAT, 0);
  setseg(3, Wd2, Wd2T, LAT, FIN, LAT, 0);
  setseg(4, Wz1, Wz1T, LAT, LAT, LAT, 0);
  setseg(5, Wz2, Wz2T, LAT, LAT, LAT, 0);
  setseg(6, Wk1, Wk1T, Dn, LAT, KP_REL, 0);
  setseg(7, Wk2, Wk2T, LAT, LAT, LAT, 0);
  setseg(8, rel_emb, rel_bf, Vn, Dn, KP_REL, 1);  // VP x KP_REL pad
  int tacc = 0;
  for (int i = 0; i < 9; ++i) {
    int rows;  // dst row count
    if (segs.s[i].mode == 0) rows = (segs.s[i].N + 63) & ~63;  // transposed: N rows
    else rows = VP;
    tacc += (rows >> 6) * (segs.s[i].Kp >> 6);
    segs.s[i].tile_end = tacc;
  }
  const int conv_tiles = tacc;

  prep_kernel<<<conv_tiles + Bn / 4, 256, 0, stream>>>(
      segs, conv_tiles, logits, rels, rel_emb, pos_keys, neg_keys, x_bf);

  auto mkseg = [](const u16* A, const u16* Bt, const float* bias, float* Cf,
                  u16* Cb, const u16* xref, float* part, int M, int N, int Kp,
                  int ldc, int act) {
    GSeg g;
    g.A = A; g.Bt = Bt; g.bias = bias; g.Cf = Cf; g.Cb = Cb;
    g.xref = xref; g.part = part;
    g.M = M; g.N = N; g.Kp = Kp; g.ldc = ldc; g.act = act;
    g.tiles_n = N > 512 ? (N + 63) / 64 : N / 64;
    if (N == FIN) g.tiles_n = KP_X / 64;  // vae: cover padded cols, guarded
    g.tile_end = 0;
    return g;
  };
  auto tiles_of = [](const GSeg& g) {
    return ((g.M + 63) / 64) * g.tiles_n;
  };
  auto launch2 = [&](GSeg a, GSeg b) {
    GSegs2 gs;
    a.tile_end = tiles_of(a);
    gs.s[0] = a;
    gs.s[1] = b;
    gemm_multi<<<a.tile_end + tiles_of(b), 256, 0, stream>>>(gs);
  };

  // A: th = relu(rel_bf @ Wk1 + bk1)  ||  t1 = tanh(x_bf @ We1 + be1)
  launch2(
      mkseg(rel_bf, Wk1T, bk1, nullptr, th_bf, nullptr, nullptr, Vn, LAT, KP_REL, LAT, 3),
      mkseg(x_bf, We1T, be1, nullptr, t1, nullptr, nullptr, Bn, LAT, KP_X, LAT, 1));
  // B: proj = th @ Wk2 + bk2  ||  zb = tanh(t1 @ We2 + be2)
  launch2(
      mkseg(th_bf, Wk2T, bk2, proj, nullptr, nullptr, nullptr, Vn, ZD, LAT, ZD, 0),
      mkseg(t1, We2T, be2, nullptr, zb, nullptr, nullptr, Bn, ZD, LAT, ZD, 1));
  // C: t2 = tanh(zb @ Wd1 + bd1)  ||  t3 = relu(zb @ Wz1 + bz1)
  launch2(
      mkseg(zb, Wd1T, bd1, nullptr, t2, nullptr, nullptr, Bn, LAT, ZD, LAT, 1),
      mkseg(zb, Wz1T, bz1, nullptr, t3, nullptr, nullptr, Bn, LAT, ZD, LAT, 3));
  // D: vae partials from sigmoid(t2 @ Wd2 + bd2) vs x_bf  ||  zp = t3 @ Wz2 + bz2
  launch2(
      mkseg(t2, Wd2T, bd2, nullptr, nullptr, x_bf, vae_part, Bn, FIN, LAT, KP_X, 2),
      mkseg(t3, Wz2T, bz2, zp_out, nullptr, nullptr, nullptr, Bn, ZD, LAT, ZD, 0));

  const int n_vae_parts = (Bn / 64) * (KP_X / 64);  // 640

  csl_kernel<<<Bn / 4, 256, 0, stream>>>(zp_out, proj, pos_keys, neg_keys, row_loss);
  finalize_kernel<<<1, 256, 0, stream>>>(vae_part, n_vae_parts, row_loss, Bn, out);
}